// Round 6
// baseline (48948.795 us; speedup 1.0000x reference)
//
#include <hip/hip_runtime.h>
#include <math.h>

#define TT 2048
#define BB 128

typedef _Float16 half8v __attribute__((ext_vector_type(8)));

// ---- d_ws layout (float offsets) ----
// [0, 1984)           bcat fp32 (b_ih+b_hh concat)
// [2048, 263680)      fp16 weights, k-major [K][G] (same as R2)
// [264192, +128 ints) aflag[pair]   (A's completed-step count, monotone)
// [264448, +128 ints) bflag[pair]   (B's completed-step count)
// [265216, 527360)    ring: [128 pair][8 slot][256] fp32 h1
#define BC_FLOATS 1984
#define H_BASE_F  2048
#define HC1 0
#define HC2 262144
#define HC3 458752
#define HC4 507904
#define HC5 520192
#define HTOT 523264
#define PREP_TOT (HTOT + BC_FLOATS)
#define AFLAG_F 264192
#define BFLAG_F 264448
#define RING_F  265216

__device__ __forceinline__ float sigf(float x) { return 1.0f / (1.0f + __expf(-x)); }

// ---------------- prep: transpose + fp16-quantize weights (same as R2) ----------------
__global__ __launch_bounds__(256)
void prep_kernel(const float* __restrict__ w1hh,
                 const float* __restrict__ w2ih, const float* __restrict__ w2hh,
                 const float* __restrict__ w3ih, const float* __restrict__ w3hh,
                 const float* __restrict__ w4ih, const float* __restrict__ w4hh,
                 const float* __restrict__ w5ih, const float* __restrict__ w5hh,
                 const float* __restrict__ b1ih, const float* __restrict__ b1hh,
                 const float* __restrict__ b2ih, const float* __restrict__ b2hh,
                 const float* __restrict__ b3ih, const float* __restrict__ b3hh,
                 const float* __restrict__ b4ih, const float* __restrict__ b4hh,
                 const float* __restrict__ b5ih, const float* __restrict__ b5hh,
                 float* __restrict__ ws)
{
    int idx = blockIdx.x * 256 + threadIdx.x;
    if (idx >= PREP_TOT) return;

    if (idx < HTOT) {
        _Float16* wsh = (_Float16*)(ws + H_BASE_F);
        float v;
        if (idx < HC2) {                       // Wc1 [256][1024] = w1hh^T
            int k = idx >> 10, j = idx & 1023;
            v = w1hh[j * 256 + k];
        } else if (idx < HC3) {                // Wc2 [384][512]
            int r = idx - HC2;
            int k = r >> 9, j = r & 511;
            v = (k < 256) ? w2ih[j * 256 + k] : w2hh[j * 128 + (k - 256)];
        } else if (idx < HC4) {                // Wc3 [192][256]
            int r = idx - HC3;
            int k = r >> 8, j = r & 255;
            v = (k < 128) ? w3ih[j * 128 + k] : w3hh[j * 64 + (k - 128)];
        } else if (idx < HC5) {                // Wc4 [96][128]
            int r = idx - HC4;
            int k = r >> 7, j = r & 127;
            v = (k < 64) ? w4ih[j * 64 + k] : w4hh[j * 32 + (k - 64)];
        } else {                               // Wc5 [48][64]
            int r = idx - HC5;
            int k = r >> 6, j = r & 63;
            v = (k < 32) ? w5ih[j * 32 + k] : w5hh[j * 16 + (k - 32)];
        }
        wsh[idx] = (_Float16)v;
    } else {
        int r = idx - HTOT;
        float v;
        if (r < 1024)      v = b1ih[r]        + b1hh[r];
        else if (r < 1536) v = b2ih[r - 1024] + b2hh[r - 1024];
        else if (r < 1792) v = b3ih[r - 1536] + b3hh[r - 1536];
        else if (r < 1920) v = b4ih[r - 1792] + b4hh[r - 1792];
        else               v = b5ih[r - 1920] + b5hh[r - 1920];
        ws[r] = v;
    }
}

__global__ __launch_bounds__(256)
void prep_zero_flags(float* __restrict__ ws) {
    int idx = blockIdx.x * 256 + threadIdx.x;           // 1024 floats of flag region
    if (idx < 1024) ws[AFLAG_F + idx] = 0.0f;           // covers aflag+bflag+pad
}

// ---------------- per-layer step (R2-proven: fp32 activations, fp16 weights) --------
// Wc: k-major [KTOT][G] halves. S k-segments, KSEG=KTOT/S. Thread (s,q) owns gate
// rows 8q..8q+7 over k-seg s (half8 per k). Combine: thread j<DH sums partials +
// bias (+ x*w1l for L1), nonlinearity, updates C[COFF+j], X[HOFF+j]; if RING also
// fire-and-forget atomic store of h to ringp[j].
template<int KTOT, int G, int DH, int S, int XK, int HOFF, int COFF, int BOFF,
         bool L1X, bool RING>
__device__ __forceinline__ void layer_step(
    const _Float16* __restrict__ Wh,
    float* __restrict__ X, float* __restrict__ C,
    float* __restrict__ partf,
    const float* __restrict__ bc, const float* __restrict__ w1l,
    const float* __restrict__ xin, int xoff,
    float* __restrict__ ringp, int tid)
{
    constexpr int G8 = G / 8;
    constexpr int KSEG = KTOT / S;
    static_assert(KTOT % S == 0, "even k-split");

    if (tid < S * G8) {
        int q = tid & (G8 - 1);
        int s = tid / G8;
        const float* xp = X + XK + s * KSEG;
        const half8v* wp = (const half8v*)Wh + (size_t)s * KSEG * G8 + q;
        float4 a0 = {0.f, 0.f, 0.f, 0.f};
        float4 a1 = {0.f, 0.f, 0.f, 0.f};
#pragma unroll 8
        for (int k = 0; k < KSEG; ++k) {
            float xx = xp[k];
            half8v w = wp[(size_t)k * G8];
            a0.x = fmaf((float)w[0], xx, a0.x);
            a0.y = fmaf((float)w[1], xx, a0.y);
            a0.z = fmaf((float)w[2], xx, a0.z);
            a0.w = fmaf((float)w[3], xx, a0.w);
            a1.x = fmaf((float)w[4], xx, a1.x);
            a1.y = fmaf((float)w[5], xx, a1.y);
            a1.z = fmaf((float)w[6], xx, a1.z);
            a1.w = fmaf((float)w[7], xx, a1.w);
        }
        float4* pp = (float4*)partf + ((s * G + 8 * q) >> 2);
        pp[0] = a0;
        pp[1] = a1;
    }
    __syncthreads();   // partials visible

    if (tid < DH) {
        float g[4];
#pragma unroll
        for (int cg = 0; cg < 4; ++cg) {
            int r = cg * DH + tid;
            float acc = bc[BOFF + r];
#pragma unroll
            for (int s2 = 0; s2 < S; ++s2) acc += partf[s2 * G + r];
            if (L1X) acc = fmaf(xin[xoff], w1l[r], acc);
            g[cg] = acc;
        }
        float ig = sigf(g[0]), fg = sigf(g[1]);
        float gg = tanhf(g[2]), og = sigf(g[3]);
        float cn = fmaf(fg, C[COFF + tid], ig * gg);
        C[COFF + tid] = cn;
        float h = og * tanhf(cn);
        X[HOFF + tid] = h;
        if (RING)
            __hip_atomic_store(ringp + tid, h, __ATOMIC_RELAXED,
                               __HIP_MEMORY_SCOPE_AGENT);
    }
    // trailing __syncthreads() supplied by caller
}

// ---------------- main: 256 blocks = 128 (A: L1) + 128 (B: L2-L5 + head) ----------
__global__ __launch_bounds__(1024)
void lstm_pipe(const float* __restrict__ inp,
               const float* __restrict__ ws,
               const float* __restrict__ w1ih,
               const float* __restrict__ wlin, const float* __restrict__ blin,
               float* __restrict__ out)
{
    __shared__ __align__(16) float part[8192];
    __shared__ __align__(16) float X[512];     // A: h1@1..257  B: h1@0,h2@256,h3@384,h4@448,h5@480
    __shared__ __align__(16) float C[512];     // A: c1@0..256  B: c2@0,c3@128,c4@192,c5@224
    __shared__ __align__(16) float Xin[64];    // A: input chunk
    __shared__ float bc[1984];
    __shared__ float w1l[1024];
    __shared__ float wl[17];

    const int tid = threadIdx.x;
    const bool isA = blockIdx.x < BB;
    const int b = isA ? blockIdx.x : (blockIdx.x - BB);

    for (int i = tid; i < 512; i += 1024) { X[i] = 0.f; C[i] = 0.f; }
    for (int i = tid; i < 1984; i += 1024) bc[i] = ws[i];
    w1l[tid < 1024 ? tid : 0] = w1ih[tid < 1024 ? tid : 0];
    if (tid < 16) wl[tid] = wlin[tid];
    if (tid == 16) wl[16] = blin[0];
    __syncthreads();

    const _Float16* Wh = (const _Float16*)(ws + H_BASE_F);
    int* aflag = (int*)(ws + AFLAG_F);
    int* bflag = (int*)(ws + BFLAG_F);
    float* ring = (float*)(ws + RING_F);

    if (isA) {
        // ---------------- A: layer 1, self-contained recurrence ----------------
        for (int t = 0; t < TT; ++t) {
            if ((t & 63) == 0 && tid < 16)
                *(float4*)(Xin + 4 * tid) =
                    *(const float4*)(inp + (size_t)b * TT + t + 4 * tid);
            __syncthreads();   // Xin + X(h1 prev) visible; also covers throttle wait

            float* ringp = ring + ((size_t)b * 8 + (t & 7)) * 256;
            layer_step<256, 1024, 256, 8, 1, 1, 0, 0, true, true>(
                Wh + HC1, X, C, part, bc, w1l, Xin, t & 63, ringp, tid);
            __syncthreads();   // combine's ring stores drained (vmcnt(0) at barrier)

            if (tid == 0) {
                __hip_atomic_store(aflag + b, t + 1, __ATOMIC_RELEASE,
                                   __HIP_MEMORY_SCOPE_AGENT);
                // throttle vs ring depth 8: ensure B consumed step t-7 and beyond
                if ((t & 3) == 3) {
                    while (__hip_atomic_load(bflag + b, __ATOMIC_RELAXED,
                                             __HIP_MEMORY_SCOPE_AGENT) < t - 3)
                        __builtin_amdgcn_s_sleep(8);
                }
            }
        }
    } else {
        // ---------------- B: layers 2-5 + linear head ----------------
        for (int t = 0; t < TT; ++t) {
            while (__hip_atomic_load(aflag + b, __ATOMIC_RELAXED,
                                     __HIP_MEMORY_SCOPE_AGENT) <= t)
                __builtin_amdgcn_s_sleep(1);
            __builtin_amdgcn_fence(__ATOMIC_ACQUIRE, "agent");

            if (tid < 256)
                X[tid] = __hip_atomic_load(
                    ring + ((size_t)b * 8 + (t & 7)) * 256 + tid,
                    __ATOMIC_RELAXED, __HIP_MEMORY_SCOPE_AGENT);
            __syncthreads();   // h1 staged; slot consumed
            if (tid == 0)
                __hip_atomic_store(bflag + b, t + 1, __ATOMIC_RELAXED,
                                   __HIP_MEMORY_SCOPE_AGENT);

            layer_step<384, 512, 128, 16, 0,   256, 0,   1024, false, false>(
                Wh + HC2, X, C, part, bc, w1l, Xin, 0, ring, tid);
            __syncthreads();
            layer_step<192, 256, 64, 16, 256, 384, 128, 1536, false, false>(
                Wh + HC3, X, C, part, bc, w1l, Xin, 0, ring, tid);
            __syncthreads();
            layer_step<96, 128, 32, 8, 384, 448, 192, 1792, false, false>(
                Wh + HC4, X, C, part, bc, w1l, Xin, 0, ring, tid);
            __syncthreads();
            layer_step<48, 64, 16, 8, 448, 480, 224, 1920, false, false>(
                Wh + HC5, X, C, part, bc, w1l, Xin, 0, ring, tid);
            __syncthreads();

            if (tid == 0) {
                float a = wl[16];
#pragma unroll
                for (int k = 0; k < 16; ++k) a = fmaf(X[480 + k], wl[k], a);
                out[(size_t)b * TT + t] = a;
            }
        }
    }
}

extern "C" void kernel_launch(void* const* d_in, const int* in_sizes, int n_in,
                              void* d_out, int out_size, void* d_ws, size_t ws_size,
                              hipStream_t stream) {
    const float* p[23];
    for (int i = 0; i < 23 && i < n_in; ++i) p[i] = (const float*)d_in[i];
    float* ws = (float*)d_ws;

    prep_kernel<<<dim3((PREP_TOT + 255) / 256), dim3(256), 0, stream>>>(
        p[2],
        p[5],  p[6],  p[9],  p[10], p[13], p[14], p[17], p[18],
        p[3],  p[4],  p[7],  p[8],  p[11], p[12], p[15], p[16],
        p[19], p[20],
        ws);
    prep_zero_flags<<<dim3(4), dim3(256), 0, stream>>>(ws);

    // ~49 KB static + 48 KB dynamic = 97 KB/block -> 1 block/CU; grid 256 = CU
    // count -> all A/B pairs co-resident (required for the flag handshake).
    lstm_pipe<<<dim3(256), dim3(1024), 49152, stream>>>(
        p[0], ws, p[1], p[21], p[22], (float*)d_out);
}

// Round 7
// 10851.307 us; speedup vs baseline: 4.5109x; 4.5109x over previous
//
#include <hip/hip_runtime.h>
#include <math.h>

#define TT 2048
#define NSTEP 2053   // 2048 + 4 pipeline fill + 1 head drain

typedef _Float16 half2v __attribute__((ext_vector_type(2)));
typedef _Float16 half8v __attribute__((ext_vector_type(8)));

#if defined(__has_builtin)
#if __has_builtin(__builtin_amdgcn_fdot2)
#define HAVE_FDOT2 1
#endif
#endif

__device__ __forceinline__ float fdot2f(half2v a, half2v b, float c) {
#ifdef HAVE_FDOT2
    return __builtin_amdgcn_fdot2(a, b, c, false);
#else
    return c + (float)a.x * (float)b.x + (float)a.y * (float)b.y;
#endif
}
__device__ __forceinline__ half2v h2at(half8v v, int m) {
    half2v r; r.x = v[2 * m]; r.y = v[2 * m + 1]; return r;
}
__device__ __forceinline__ float sigf(float x) { return 1.0f / (1.0f + __expf(-x)); }
__device__ __forceinline__ float tanh_f(float x) {
    float t = __expf(fminf(2.0f * x, 30.0f));
    return (t - 1.0f) / (t + 1.0f);
}

// ---- d_ws layout (bytes) ----
// [0, 262144)   board: u64 [2 parity][32 group][512 h]  (each u64 = 4 batch fp16)
// [262144, +16K) flags: int [32 group][8 member] stride 16 ints (monotone step cnt)
#define FLAGS_BOFF 262144
#define ZERO_F4    17408     // float4 count covering board+flags

// ---- dynamic LDS layout (halves). Row strides chosen for 16B alignment;
// adjacent rows offset 4 banks -> worst 2-way aliasing (free on CDNA4).
#define K1STR 264
#define K2STR 392
#define K3STR 200
#define K4STR 104
#define K5STR 72
#define XSTR  520
#define W1_OFF 0
#define W2_OFF 33792
#define W3_OFF 58880
#define W4_OFF 65280
#define W5_OFF 66944
#define X_OFF  67520
#define LDS_BYTES 139264     // 69600 halves rounded up

__global__ __launch_bounds__(256)
void prep_zero(float4* ws) {
    int idx = blockIdx.x * 256 + threadIdx.x;
    if (idx < ZERO_F4) ws[idx] = make_float4(0.f, 0.f, 0.f, 0.f);
}

// One layer slice: RG h-units (of this block's shard), rows r = rg + RG*i (gate i).
// KG-way k-split, J iters of 8k. Butterfly reduce over kg -> ALL lanes hold all
// 16 sums; lane kg<4 owns batch j=kg (c in its register), computes nonlinearity;
// lane kg==0 gathers 4 h via shfl, one 8B relaxed store to board. NO fences.
template<int RG, int KG, int J, int KOFF, int KSTR, int HBASE, bool ISL1>
__device__ __forceinline__ void layer_g8(
    const _Float16* __restrict__ W, const float* __restrict__ bias,
    const _Float16* __restrict__ Xs,
    unsigned long long* __restrict__ bdst,
    const float* __restrict__ w1xl, const float* __restrict__ xinl, int xoff,
    float& cpriv, int u, int lane, int m)
{
    const int kg = u & (KG - 1);
    const int rg = u / KG;

    float acc[4][4];
#pragma unroll
    for (int i = 0; i < 4; ++i)
#pragma unroll
        for (int j = 0; j < 4; ++j) acc[i][j] = 0.f;

#pragma unroll
    for (int jj = 0; jj < J; ++jj) {
        const int kk = kg * 8 + jj * (KG * 8);
        half8v xv[4], wv[4];
#pragma unroll
        for (int j = 0; j < 4; ++j)
            xv[j] = *(const half8v*)(Xs + j * XSTR + KOFF + kk);
#pragma unroll
        for (int i = 0; i < 4; ++i)
            wv[i] = *(const half8v*)(W + (rg + RG * i) * KSTR + kk);
#pragma unroll
        for (int i = 0; i < 4; ++i)
#pragma unroll
            for (int j = 0; j < 4; ++j)
#pragma unroll
                for (int mm = 0; mm < 4; ++mm)
                    acc[i][j] = fdot2f(h2at(wv[i], mm), h2at(xv[j], mm), acc[i][j]);
    }

#pragma unroll
    for (int d = 1; d < KG; d <<= 1)
#pragma unroll
        for (int i = 0; i < 4; ++i)
#pragma unroll
            for (int j = 0; j < 4; ++j)
                acc[i][j] += __shfl_xor(acc[i][j], d, 64);

    float h = 0.f;
    if (kg < 4) {
        const int j = kg;
        float g0 = acc[0][j] + bias[rg];
        float g1 = acc[1][j] + bias[rg + RG];
        float g2 = acc[2][j] + bias[rg + 2 * RG];
        float g3 = acc[3][j] + bias[rg + 3 * RG];
        if (ISL1) {
            float xt = xinl[j * 64 + xoff];
            g0 = fmaf(w1xl[rg], xt, g0);
            g1 = fmaf(w1xl[rg + RG], xt, g1);
            g2 = fmaf(w1xl[rg + 2 * RG], xt, g2);
            g3 = fmaf(w1xl[rg + 3 * RG], xt, g3);
        }
        float ig = sigf(g0), fg = sigf(g1), gg = tanh_f(g2), og = sigf(g3);
        float cn = fmaf(fg, cpriv, ig * gg);
        cpriv = cn;
        h = og * tanh_f(cn);
    }
    union { _Float16 hf; unsigned short us; } cv;
    cv.hf = (_Float16)h;
    const int base = lane & ~(KG - 1);
    unsigned long long p0 = (unsigned short)__shfl((int)cv.us, base + 0, 64);
    unsigned long long p1 = (unsigned short)__shfl((int)cv.us, base + 1, 64);
    unsigned long long p2 = (unsigned short)__shfl((int)cv.us, base + 2, 64);
    unsigned long long p3 = (unsigned short)__shfl((int)cv.us, base + 3, 64);
    if (kg == 0) {
        unsigned long long packed = p0 | (p1 << 16) | (p2 << 32) | (p3 << 48);
        __hip_atomic_store(bdst + (HBASE + m * RG + rg), packed,
                           __ATOMIC_RELAXED, __HIP_MEMORY_SCOPE_AGENT);
    }
}

__global__ __launch_bounds__(512)
void lstm_g8(const float* __restrict__ inp,
             const float* __restrict__ w1ih, const float* __restrict__ w1hh,
             const float* __restrict__ b1ih, const float* __restrict__ b1hh,
             const float* __restrict__ w2ih, const float* __restrict__ w2hh,
             const float* __restrict__ b2ih, const float* __restrict__ b2hh,
             const float* __restrict__ w3ih, const float* __restrict__ w3hh,
             const float* __restrict__ b3ih, const float* __restrict__ b3hh,
             const float* __restrict__ w4ih, const float* __restrict__ w4hh,
             const float* __restrict__ b4ih, const float* __restrict__ b4hh,
             const float* __restrict__ w5ih, const float* __restrict__ w5hh,
             const float* __restrict__ b5ih, const float* __restrict__ b5hh,
             const float* __restrict__ wlin, const float* __restrict__ blin,
             float* __restrict__ out, char* __restrict__ wsb)
{
    extern __shared__ __align__(16) _Float16 smem[];
    _Float16* Wl1 = smem + W1_OFF;
    _Float16* Wl2 = smem + W2_OFF;
    _Float16* Wl3 = smem + W3_OFF;
    _Float16* Wl4 = smem + W4_OFF;
    _Float16* Wl5 = smem + W5_OFF;
    _Float16* Xs  = smem + X_OFF;

    __shared__ float Xin[256];                 // [4 b][64 t] input chunk
    __shared__ float bias1[128], bias2[64], bias3[32], bias4[16], bias5[8];
    __shared__ float w1xl[128], wlin_s[16], blin_s;

    const int tid = threadIdx.x;
    const int g = blockIdx.x & 31;     // group (members share mod-8 class -> XCD heuristic)
    const int m = blockIdx.x >> 5;     // member 0..7
    const int lane = tid & 63;

    // ---- init: stage fp16 weight shards into LDS (read-once from HBM) ----
    for (int idx = tid; idx < 128 * 256; idx += 512) {
        int r = idx >> 8, k = idx & 255;
        int i = r >> 5, rg = r & 31;
        int grow = i * 256 + m * 32 + rg;
        Wl1[r * K1STR + k] = (_Float16)w1hh[grow * 256 + k];
    }
    for (int idx = tid; idx < 64 * 384; idx += 512) {
        int r = idx / 384, k = idx - r * 384;
        int i = r >> 4, rg = r & 15;
        int grow = i * 128 + m * 16 + rg;
        float v = (k < 256) ? w2ih[grow * 256 + k] : w2hh[grow * 128 + (k - 256)];
        Wl2[r * K2STR + k] = (_Float16)v;
    }
    for (int idx = tid; idx < 32 * 192; idx += 512) {
        int r = idx / 192, k = idx - r * 192;
        int i = r >> 3, rg = r & 7;
        int grow = i * 64 + m * 8 + rg;
        float v = (k < 128) ? w3ih[grow * 128 + k] : w3hh[grow * 64 + (k - 128)];
        Wl3[r * K3STR + k] = (_Float16)v;
    }
    for (int idx = tid; idx < 16 * 96; idx += 512) {
        int r = idx / 96, k = idx - r * 96;
        int i = r >> 2, rg = r & 3;
        int grow = i * 32 + m * 4 + rg;
        float v = (k < 64) ? w4ih[grow * 64 + k] : w4hh[grow * 32 + (k - 64)];
        Wl4[r * K4STR + k] = (_Float16)v;
    }
    for (int idx = tid; idx < 8 * 64; idx += 512) {      // L5 k-padded to 64
        int r = idx >> 6, k = idx & 63;
        int i = r >> 1, rg = r & 1;
        int grow = i * 16 + m * 2 + rg;
        float v = (k < 32) ? w5ih[grow * 32 + k]
                           : (k < 48 ? w5hh[grow * 16 + (k - 32)] : 0.f);
        Wl5[r * K5STR + k] = (_Float16)v;
    }
    for (int idx = tid; idx < 4 * XSTR; idx += 512) Xs[idx] = (_Float16)0.f;

    if (tid < 128) {
        int i = tid >> 5, rg = tid & 31;
        int grow = i * 256 + m * 32 + rg;
        bias1[tid] = b1ih[grow] + b1hh[grow];
        w1xl[tid] = w1ih[grow];
    } else if (tid < 192) {
        int u = tid - 128; int i = u >> 4, rg = u & 15;
        int grow = i * 128 + m * 16 + rg;
        bias2[u] = b2ih[grow] + b2hh[grow];
    } else if (tid < 224) {
        int u = tid - 192; int i = u >> 3, rg = u & 7;
        int grow = i * 64 + m * 8 + rg;
        bias3[u] = b3ih[grow] + b3hh[grow];
    } else if (tid < 240) {
        int u = tid - 224; int i = u >> 2, rg = u & 3;
        int grow = i * 32 + m * 4 + rg;
        bias4[u] = b4ih[grow] + b4hh[grow];
    } else if (tid < 248) {
        int u = tid - 240; int i = u >> 1, rg = u & 1;
        int grow = i * 16 + m * 2 + rg;
        bias5[u] = b5ih[grow] + b5hh[grow];
    } else if (tid < 264) {
        wlin_s[tid - 248] = wlin[tid - 248];
    } else if (tid == 264) {
        blin_s = blin[0];
    }
    __syncthreads();

    unsigned long long* board = (unsigned long long*)wsb;
    int* flags = (int*)(wsb + FLAGS_BOFF);
    float cpriv = 0.f;

    for (int s = 0; s < NSTEP; ++s) {
        const int pr = (s + 1) & 1, pw = s & 1;

        // ---- stage board[pr] -> Xs (fp16, [b][h]); 8B relaxed loads, no fence ----
        const unsigned long long* bsrc = board + (size_t)(pr * 32 + g) * 512;
        if (tid < 496) {
            unsigned long long v = __hip_atomic_load(
                bsrc + tid, __ATOMIC_RELAXED, __HIP_MEMORY_SCOPE_AGENT);
            unsigned short* Xu = (unsigned short*)Xs;
            Xu[0 * XSTR + tid] = (unsigned short)(v);
            Xu[1 * XSTR + tid] = (unsigned short)(v >> 16);
            Xu[2 * XSTR + tid] = (unsigned short)(v >> 32);
            Xu[3 * XSTR + tid] = (unsigned short)(v >> 48);
        } else if (((s & 63) == 0) && s < TT) {
            // tid 496..511 unused here; Xin loaded by tid 448..511 below instead
        }
        if (((s & 63) == 0) && s < TT && tid >= 448) {
            int u = tid - 448;                 // 64 lanes
            int b = u >> 4, t4 = (u & 15) << 2;
            *(float4*)(Xin + b * 64 + t4) =
                *(const float4*)(inp + (size_t)(g * 4 + b) * TT + s + t4);
        }
        __syncthreads();

        unsigned long long* bdst = board + (size_t)(pw * 32 + g) * 512;
        const int xoff = s & 63;

        // ---- diagonal layer pipeline on disjoint wave ranges ----
        if (tid < 256) {
            if (s < 2048)
                layer_g8<32, 8, 4, 0, K1STR, 0, true>(
                    Wl1, bias1, Xs, bdst, w1xl, Xin, xoff, cpriv, tid, lane, m);
        } else if (tid < 384) {
            if (s >= 1 && s <= 2048)
                layer_g8<16, 8, 6, 0, K2STR, 256, false>(
                    Wl2, bias2, Xs, bdst, w1xl, Xin, 0, cpriv, tid - 256, lane, m);
        } else if (tid < 448) {
            if (s >= 2 && s <= 2049)
                layer_g8<8, 8, 3, 256, K3STR, 384, false>(
                    Wl3, bias3, Xs, bdst, w1xl, Xin, 0, cpriv, tid - 384, lane, m);
        } else if (tid < 464) {
            if (s >= 3 && s <= 2050)
                layer_g8<4, 4, 3, 384, K4STR, 448, false>(
                    Wl4, bias4, Xs, bdst, w1xl, Xin, 0, cpriv, tid - 448, lane, m);
        } else if (tid < 472) {
            if (s >= 4 && s <= 2051)
                layer_g8<2, 4, 2, 448, K5STR, 480, false>(
                    Wl5, bias5, Xs, bdst, w1xl, Xin, 0, cpriv, tid - 464, lane, m);
        } else if (tid < 476) {
            if (m == 0 && s >= 5) {
                int b = tid - 472;
                float a = blin_s;
#pragma unroll
                for (int j = 0; j < 16; ++j)
                    a = fmaf((float)Xs[b * XSTR + 480 + j], wlin_s[j], a);
                out[(size_t)(g * 4 + b) * TT + (s - 5)] = a;
            }
        }

        // ---- fence-free group barrier: __syncthreads drains vmcnt(0) per wave,
        // so all board stores are globally visible before the flag store issues.
        __syncthreads();
        if (tid == 0)
            __hip_atomic_store(flags + (g * 8 + m) * 16, s + 1,
                               __ATOMIC_RELAXED, __HIP_MEMORY_SCOPE_AGENT);
        if (tid < 8) {
            const int* fp = flags + (g * 8 + tid) * 16;
            while (__hip_atomic_load(fp, __ATOMIC_RELAXED,
                                     __HIP_MEMORY_SCOPE_AGENT) <= s)
                __builtin_amdgcn_s_sleep(1);
        }
        __syncthreads();
    }
}

extern "C" void kernel_launch(void* const* d_in, const int* in_sizes, int n_in,
                              void* d_out, int out_size, void* d_ws, size_t ws_size,
                              hipStream_t stream) {
    const float* p[23];
    for (int i = 0; i < 23 && i < n_in; ++i) p[i] = (const float*)d_in[i];

    // allow >64KB dynamic LDS (idempotent; ignore error if unsupported/unneeded)
    (void)hipFuncSetAttribute((const void*)lstm_g8,
                              hipFuncAttributeMaxDynamicSharedMemorySize,
                              LDS_BYTES);

    prep_zero<<<dim3((ZERO_F4 + 255) / 256), dim3(256), 0, stream>>>((float4*)d_ws);

    // ~136KB dynamic + ~2.5KB static LDS -> 1 block/CU; grid 256 = CU count ->
    // all 32 groups x 8 members co-resident (required for the flag barrier).
    lstm_g8<<<dim3(256), dim3(512), LDS_BYTES, stream>>>(
        p[0],
        p[1],  p[2],  p[3],  p[4],
        p[5],  p[6],  p[7],  p[8],
        p[9],  p[10], p[11], p[12],
        p[13], p[14], p[15], p[16],
        p[17], p[18], p[19], p[20],
        p[21], p[22],
        (float*)d_out, (char*)d_ws);
}